// Round 1
// baseline (140.643 us; speedup 1.0000x reference)
//
#include <hip/hip_runtime.h>
#include <math.h>

// Problem constants (match reference).
constexpr int kN      = 5;
constexpr int kB      = 1048576;
constexpr int kBN     = kB * kN;        // 5242880 elements per output plane
constexpr int kBN4    = kBN / 4;        // 1310720 float4 groups per plane
constexpr int kSteps  = 10;
constexpr int kBlocks = 1280;           // 5 blocks/CU; kBN4 / (1280*256) = 4 iters exactly
constexpr int kThreads = 256;

// One dynamics evaluation. Lane i (within wave 0) owns oscillator i; lanes 5..63
// mirror lane 0 (results ignored) so all 64 lanes participate in the shuffles.
__device__ __forceinline__ void cpg_dynamics(float r, float rd, float th,
                                             float mu, float a,
                                             const float wr[kN], const float ph[kN],
                                             float freq, float& rdd, float& thd)
{
    rdd = a * (a * 0.25f * (mu - r) - rd);
    float coup = 0.f;
#pragma unroll
    for (int j = 0; j < kN; ++j) {
        float th_j = __shfl(th, j);
        float r_j  = __shfl(r, j);
        coup = __builtin_fmaf(wr[j] * __sinf(th_j - th - ph[j]), r_j, coup);
    }
    thd = freq + coup;
}

__device__ __forceinline__ float softplus_f(float x)
{
    // stable: max(x,0) + log1p(exp(-|x|))
    return fmaxf(x, 0.f) + log1pf(expf(-fabsf(x)));
}

__global__ __launch_bounds__(kThreads)
void ijspeert_kernel(const float* __restrict__ t,
                     const float* __restrict__ dt_p,
                     const float* __restrict__ mu_p,
                     const float* __restrict__ a_p,
                     const float* __restrict__ w_p,
                     const float* __restrict__ phi_p,
                     const float* __restrict__ freq_p,
                     const float* __restrict__ amp_p,
                     const float* __restrict__ phase_p,
                     const float* __restrict__ std_p,
                     float* __restrict__ out)
{
    __shared__ float s_amp[kN], s_w2[kN], s_p[kN], s_std[kN], s_r[kN], s_th[kN];

    // ---- Preamble: batch-independent RK4 solve, wave 0 only, 5 live lanes ----
    if (threadIdx.x < 64) {
        const int i = (threadIdx.x < kN) ? (int)threadIdx.x : 0;
        const float dt = dt_p[0];
        const float mu = mu_p[i];
        const float a  = a_p[i];
        const float fr = freq_p[i];
        float wr[kN], ph[kN];
#pragma unroll
        for (int j = 0; j < kN; ++j) {
            wr[j] = w_p[i * kN + j];
            ph[j] = phi_p[i * kN + j];
        }

        float r = 0.f, rd = 0.f, th = 0.f;
        for (int s = 0; s < kSteps; ++s) {
            float rdd1, td1, rdd2, td2, rdd3, td3, rdd4, td4;
            cpg_dynamics(r, rd, th, mu, a, wr, ph, fr, rdd1, td1);
            const float k1_r = rd, k1_rd = rdd1, k1_t = td1;
            cpg_dynamics(r + 0.5f * dt * k1_r, rd + 0.5f * dt * k1_rd,
                         th + 0.5f * dt * k1_t, mu, a, wr, ph, fr, rdd2, td2);
            const float k2_r = rd + 0.5f * dt * k1_rd, k2_rd = rdd2, k2_t = td2;
            cpg_dynamics(r + 0.5f * dt * k2_r, rd + 0.5f * dt * k2_rd,
                         th + 0.5f * dt * k2_t, mu, a, wr, ph, fr, rdd3, td3);
            const float k3_r = rd + 0.5f * dt * k2_rd, k3_rd = rdd3, k3_t = td3;
            cpg_dynamics(r + dt * k3_r, rd + dt * k3_rd,
                         th + dt * k3_t, mu, a, wr, ph, fr, rdd4, td4);
            const float k4_r = rd + dt * k3_rd, k4_rd = rdd4, k4_t = td4;
            const float c = dt * (1.f / 6.f);
            r  += c * (k1_r  + 2.f * k2_r  + 2.f * k3_r  + k4_r);
            rd += c * (k1_rd + 2.f * k2_rd + 2.f * k3_rd + k4_rd);
            th += c * (k1_t  + 2.f * k2_t  + 2.f * k3_t  + k4_t);
        }

        if (threadIdx.x < kN) {
            const float pi  = 3.14159265358979323846f;
            const float rng = (i & 1) ? pi : (0.5f * pi);   // RANGE = {pi/2,pi,pi/2,pi,pi/2}
            const float f_true = softplus_f(fr);
            s_w2[i]  = 2.f * pi * f_true;
            s_amp[i] = tanhf(amp_p[i]) * rng;
            s_p[i]   = softplus_f(phase_p[i]);
            s_std[i] = std_p[i];
            s_r[i]   = r;
            s_th[i]  = th;
        }
    }
    __syncthreads();

    // ---- Streaming epilogue: write [4, B, N] planes, float4-vectorized ----
    const unsigned stride = kBlocks * kThreads;
    unsigned gid = blockIdx.x * kThreads + threadIdx.x;
    float4* o = reinterpret_cast<float4*>(out);

    for (unsigned q = gid; q < (unsigned)kBN4; q += stride) {
        const unsigned f0 = q * 4u;
        float vm[4], vs[4], vr[4], vt[4];
#pragma unroll
        for (int k = 0; k < 4; ++k) {
            const unsigned fk = f0 + (unsigned)k;
            const unsigned b  = fk / 5u;         // magic-mul division
            const unsigned i  = fk - b * 5u;
            const float tb  = t[b];
            const float arg = __builtin_fmaf(s_w2[i], tb, s_p[i]);
            vm[k] = s_amp[i] * __sinf(arg);
            vs[k] = s_std[i];
            vr[k] = s_r[i];
            vt[k] = s_th[i];
        }
        o[q]                = make_float4(vm[0], vm[1], vm[2], vm[3]);
        o[kBN4 + q]         = make_float4(vs[0], vs[1], vs[2], vs[3]);
        o[2 * kBN4 + q]     = make_float4(vr[0], vr[1], vr[2], vr[3]);
        o[3 * kBN4 + q]     = make_float4(vt[0], vt[1], vt[2], vt[3]);
    }
}

extern "C" void kernel_launch(void* const* d_in, const int* in_sizes, int n_in,
                              void* d_out, int out_size, void* d_ws, size_t ws_size,
                              hipStream_t stream)
{
    // setup_inputs order:
    // 0: obs [B,10] (unused)   1: t [B]        2: dt [1]
    // 3: mu_p [N]  4: a [N]    5: w [N,N]      6: phi [N,N]
    // 7: frequencies [N]  8: amplitudes [N]  9: phases [N]  10: std [N]
    const float* t      = (const float*)d_in[1];
    const float* dt     = (const float*)d_in[2];
    const float* mu_p   = (const float*)d_in[3];
    const float* a      = (const float*)d_in[4];
    const float* w      = (const float*)d_in[5];
    const float* phi    = (const float*)d_in[6];
    const float* freq   = (const float*)d_in[7];
    const float* amp    = (const float*)d_in[8];
    const float* phase  = (const float*)d_in[9];
    const float* stdv   = (const float*)d_in[10];
    float* out = (float*)d_out;

    ijspeert_kernel<<<kBlocks, kThreads, 0, stream>>>(
        t, dt, mu_p, a, w, phi, freq, amp, phase, stdv, out);
}